// Round 6
// baseline (246.378 us; speedup 1.0000x reference)
//
#include <hip/hip_runtime.h>

#define WINDOW 13
#define NTOT   53248      // 13*64*64 voxels per (b,c)
#define WPB    4          // windows per block
#define VT     52         // real voxels per block (4 windows)
#define VS     64         // staged voxels (4 MFMA col-tiles of 16)
#define XS     72         // f16 row stride for xT/wbf/vpad (144 B: 16B-aligned, (r+g)%8 quads -> conflict-free b128)
#define QKTS   24         // qkT f16 row stride (48 B: 16B-aligned, 3r%8 quads -> conflict-free)

typedef float  floatx4 __attribute__((ext_vector_type(4)));
typedef _Float16 f16x8 __attribute__((ext_vector_type(8)));
typedef __fp16   fp16x2 __attribute__((ext_vector_type(2)));   // return type of cvt_pkrtz

__device__ __forceinline__ unsigned int pkh2(float a, float b) {
    union { fp16x2 h; unsigned int u; } c;
    c.h = __builtin_amdgcn_cvt_pkrtz(a, b);   // v_cvt_pkrtz_f16_f32, 1 inst
    return c.u;
}
__device__ __forceinline__ unsigned short cvt1(float a) {
    union { _Float16 h; unsigned short u; } c;
    c.h = (_Float16)a;                        // v_cvt_f16_f32 (RNE)
    return c.u;
}

// ---- prep: weights fp32 -> f16 packed in workspace (once per launch) ----
// ws layout: f16 w[80][64] (rows 0..7 q, 8..15 k, 16..79 v) = 10240 B, then f32 bias[80].
__global__ __launch_bounds__(256)
void prep_kernel(const float* __restrict__ wq, const float* __restrict__ bq,
                 const float* __restrict__ wk, const float* __restrict__ bk,
                 const float* __restrict__ wv, const float* __restrict__ bv,
                 unsigned short* __restrict__ ws)
{
    const int f = blockIdx.x * 256 + threadIdx.x;   // 0..767
    if (f < 640) {
        const int r = f >> 3, cw = (f & 7) * 8;
        const float* src = (r < 8)  ? (wq + r * 64 + cw)
                         : (r < 16) ? (wk + (r - 8) * 64 + cw)
                                    : (wv + (r - 16) * 64 + cw);
        const float4 w0 = *(const float4*)src;
        const float4 w1 = *(const float4*)(src + 4);
        uint4 pk;
        pk.x = pkh2(w0.x, w0.y); pk.y = pkh2(w0.z, w0.w);
        pk.z = pkh2(w1.x, w1.y); pk.w = pkh2(w1.z, w1.w);
        *(uint4*)(ws + r * 64 + cw) = pk;
    } else if (f < 720) {
        const int t = f - 640;
        const float bb = (t < 8) ? bq[t] : (t < 16) ? bk[t - 8] : bv[t - 16];
        ((float*)(ws + 5120))[t] = bb;
    }
}

// 512 threads, 33344 B LDS -> 4 blocks/CU = 32 waves/CU (100% thread occupancy).
// Grid 8192 blocks = exactly 8 rounds of 1024 CU-slots (no ragged tail).
__global__ __launch_bounds__(512, 8)
void attn_win13_kernel(const float* __restrict__ x,
                       const unsigned short* __restrict__ ws,
                       float* __restrict__ out)
{
    // LDS: 9216 + 11520 + 320 + 9216 + 3072 = 33344 B
    __shared__ __align__(16) unsigned short xT[VS * XS];    // f16 x, [vox][ch]
    __shared__ __align__(16) unsigned short wbf[80 * XS];   // f16 weights; attb aliases after P2
    __shared__ float ball[80];
    __shared__ __align__(16) unsigned short vpad[64 * XS];  // f16 v, [ch][w*16+j], j=13..15 zeroed
    __shared__ __align__(16) unsigned short qkT[VS * QKTS]; // f16 q/k, [vox][ch] (0..7 q, 8..15 k)
    unsigned short* const attb = (unsigned short*)wbf;      // [w][16][16] f16 = 2048 B

    const int tid = threadIdx.x;
    const int b   = blockIdx.y;
    const int v0  = blockIdx.x * VT;
    const size_t total = (size_t)512 * NTOT;

    // ---- P1: staging. ----
    {   // x: 64 vox x 64 ch. Thread owns 2 ch x 4 vox: 2 float4 loads, 4 pkrtz, 4 b32 writes.
        const int vq = tid >> 5, cp = tid & 31;
        const int c = cp * 2, vx = vq * 4;
        size_t i0 = (size_t)(b * 64 + c) * NTOT + v0 + vx;
        size_t i1 = i0 + NTOT;
        if (i0 > total - 4) i0 = total - 4;   // clamp tail (garbage staged cols)
        if (i1 > total - 4) i1 = total - 4;
        const float4 x0 = *(const float4*)(x + i0);
        const float4 x1 = *(const float4*)(x + i1);
        *(unsigned int*)(&xT[(vx + 0) * XS + c]) = pkh2(x0.x, x1.x);
        *(unsigned int*)(&xT[(vx + 1) * XS + c]) = pkh2(x0.y, x1.y);
        *(unsigned int*)(&xT[(vx + 2) * XS + c]) = pkh2(x0.z, x1.z);
        *(unsigned int*)(&xT[(vx + 3) * XS + c]) = pkh2(x0.w, x1.w);
    }
    {   // weights: 640 pre-packed uint4 items (f16) -> LDS; 128 threads do a 2nd item.
        int f = tid;
#pragma unroll
        for (int it = 0; it < 2; ++it, f += 512) {
            if (f < 640) {
                const int r = f >> 3, cw = (f & 7) * 8;
                const uint4 pk = *(const uint4*)(ws + r * 64 + cw);
                *(uint4*)(&wbf[r * XS + cw]) = pk;
            }
        }
    }
    if (tid < 80) ball[tid] = ((const float*)(ws + 5120))[tid];
    if (tid < 256) {   // zero vpad pad cols j=13..15 (NaN hygiene for P4 A-frag)
        const int r = tid >> 2, w = tid & 3;
        const int base = r * XS + w * 16;
        vpad[base + 13] = 0;
        *(unsigned int*)(&vpad[base + 14]) = 0u;
    }
    __syncthreads();

    // ---- P2: projection GEMM, 5 mt x 4 nt = 20 tiles over 8 waves, K=64 (2 mfma).
    // All tiles use A=xT (rows=vox), B=wbf (rows=ch): D row=(g*4+r)=vox-in-tile, col=ch.
    // mt==0 -> qkT[vox][ch] f16 scatter; mt>=1 -> vpad[ch][w*16+j] f16 scatter. ----
    {
        const int wid  = tid >> 6;
        const int lane = tid & 63;
        const int col  = lane & 15;
        const int g    = lane >> 4;
        for (int t = wid; t < 20; t += 8) {
            const int mt = t >> 2, nt = t & 3;
            const f16x8 xa0 = *(const f16x8*)(&xT [(nt * 16 + col) * XS + g * 8]);
            const f16x8 wa0 = *(const f16x8*)(&wbf[(mt * 16 + col) * XS + g * 8]);
            const f16x8 xa1 = *(const f16x8*)(&xT [(nt * 16 + col) * XS + 32 + g * 8]);
            const f16x8 wa1 = *(const f16x8*)(&wbf[(mt * 16 + col) * XS + 32 + g * 8]);
            floatx4 acc = {0.f, 0.f, 0.f, 0.f};
            acc = __builtin_amdgcn_mfma_f32_16x16x32_f16(xa0, wa0, acc, 0, 0, 0);
            acc = __builtin_amdgcn_mfma_f32_16x16x32_f16(xa1, wa1, acc, 0, 0, 0);
            const int vox = nt * 16 + g * 4;
            if (mt == 0) {                    // q/k: ch=col (0..7 q, 8..15 k)
                const float qkb = ball[col];
#pragma unroll
                for (int r = 0; r < 4; ++r)
                    qkT[(vox + r) * QKTS + col] = cvt1(acc[r] + qkb);
            } else {                          // v: ch = (mt-1)*16+col
                const int c_out = (mt - 1) * 16 + col;
                const float vb = ball[16 + c_out];
                int w = vox / 13, j = vox - w * 13;
#pragma unroll
                for (int r = 0; r < 4; ++r) {
                    if (w < WPB) vpad[c_out * XS + w * 16 + j] = cvt1(acc[r] + vb);
                    if (++j == 13) { j = 0; ++w; }
                }
            }
        }
    }
    __syncthreads();

    // ---- P3: scores via MFMA + fused in-register softmax. Wave wid<4 handles window w=wid.
    // scores[i][j] = sum_{o<8} q[o][i]*k[o][j]: A g=0 reads qkT[w13+col][0..7] (q),
    // B g=0 reads qkT[w13+col][8..15] (k); higher-g chunks zeroed. D: i=g*4+r, j=col.
    // Softmax over j = 16-lane shfl_xor reduce (j>=13 forced to -1e30 -> p=0). ----
    if (tid < 256) {
        const int wid  = tid >> 6;           // window
        const int lane = tid & 63;
        const int col  = lane & 15;
        const int g    = lane >> 4;
        const f16x8 z = {};
        const f16x8 af = (g < 2) ? *(const f16x8*)(&qkT[(wid * 13 + col) * QKTS + g * 8]) : z;
        const f16x8 bf = (g == 0) ? *(const f16x8*)(&qkT[(wid * 13 + col) * QKTS + 8]) : z;
        floatx4 acc = {0.f, 0.f, 0.f, 0.f};
        acc = __builtin_amdgcn_mfma_f32_16x16x32_f16(af, bf, acc, 0, 0, 0);
#pragma unroll
        for (int r = 0; r < 4; ++r) {
            const float s = (col < 13) ? acc[r] : -1e30f;
            float m = s;
            m = fmaxf(m, __shfl_xor(m, 1));
            m = fmaxf(m, __shfl_xor(m, 2));
            m = fmaxf(m, __shfl_xor(m, 4));
            m = fmaxf(m, __shfl_xor(m, 8));
            const float e = __expf(s - m);
            float sum = e;
            sum += __shfl_xor(sum, 1);
            sum += __shfl_xor(sum, 2);
            sum += __shfl_xor(sum, 4);
            sum += __shfl_xor(sum, 8);
            attb[wid * 256 + (g * 4 + r) * 16 + col] = cvt1(e / sum);
        }
    }
    __syncthreads();

    // ---- P4: out via MFMA. Wave wid: w=wid>>1, ct in {2(wid&1), +1}.
    // D[c][i] = sum_j v[c][j]*att[i][j]: A=vpad rows (c=col), B=attb rows (i=col),
    // k=j padded 13->16, chunks g>=2 zero-B / dup-A. D: c=ct*16+g*4+r, i=col. ----
    {
        const int wid  = tid >> 6;
        const int lane = tid & 63;
        const int col  = lane & 15;
        const int g    = lane >> 4;
        const int gA   = g & 1;
        const int w    = wid >> 1;
        const f16x8 z = {};
        const f16x8 bfrag = (g < 2) ? *(const f16x8*)(&attb[w * 256 + col * 16 + g * 8]) : z;
        const size_t obase = (size_t)(b * 64) * NTOT + v0 + w * 13 + col;
#pragma unroll
        for (int q = 0; q < 2; ++q) {
            const int ct = (wid & 1) * 2 + q;
            const f16x8 afrag = *(const f16x8*)(&vpad[(ct * 16 + col) * XS + w * 16 + gA * 8]);
            floatx4 acc = {0.f, 0.f, 0.f, 0.f};
            acc = __builtin_amdgcn_mfma_f32_16x16x32_f16(afrag, bfrag, acc, 0, 0, 0);
            if (col < 13) {
                float* op = out + obase + (size_t)(ct * 16 + g * 4) * NTOT;
                op[0]                = acc[0];
                op[(size_t)NTOT]     = acc[1];
                op[(size_t)2 * NTOT] = acc[2];
                op[(size_t)3 * NTOT] = acc[3];
            }
        }
    }
}

extern "C" void kernel_launch(void* const* d_in, const int* in_sizes, int n_in,
                              void* d_out, int out_size, void* d_ws, size_t ws_size,
                              hipStream_t stream) {
    const float* x  = (const float*)d_in[0];
    const float* wq = (const float*)d_in[1];
    const float* bq = (const float*)d_in[2];
    const float* wk = (const float*)d_in[3];
    const float* bk = (const float*)d_in[4];
    const float* wv = (const float*)d_in[5];
    const float* bv = (const float*)d_in[6];
    float* out = (float*)d_out;
    unsigned short* ws = (unsigned short*)d_ws;   // 10560 B used

    prep_kernel<<<dim3(3), dim3(256), 0, stream>>>(wq, bq, wk, bk, wv, bv, ws);

    dim3 grid(NTOT / VT, 8);   // 1024 tiles x 8 batches = 8192 blocks = 8 full rounds of 1024 slots
    dim3 block(512);
    attn_win13_kernel<<<grid, block, 0, stream>>>(x, ws, out);
}

// Round 7
// 231.136 us; speedup vs baseline: 1.0659x; 1.0659x over previous
//
#include <hip/hip_runtime.h>

#define WINDOW 13
#define NTOT   53248      // 13*64*64 voxels per (b,c)
#define WPB    8          // windows per block
#define VT     104        // real voxels per block (8 windows)
#define VS     112        // staged voxels (7 MFMA col-tiles of 16)
#define XS     72         // f16 row stride for xT/wbf (144 B: 16B-aligned, conflict-free b128)
#define QKTS   24         // qkT f16 row stride (48 B, 16B-aligned)
#define VPS    132        // vpad f16 row stride (8 win * 16 + 4 pad; 264 B -> 2-bank step, ~conflict-free)

typedef float  floatx4 __attribute__((ext_vector_type(4)));
typedef _Float16 f16x8 __attribute__((ext_vector_type(8)));
typedef __fp16   fp16x2 __attribute__((ext_vector_type(2)));   // return type of cvt_pkrtz

__device__ __forceinline__ unsigned int pkh2(float a, float b) {
    union { fp16x2 h; unsigned int u; } c;
    c.h = __builtin_amdgcn_cvt_pkrtz(a, b);   // v_cvt_pkrtz_f16_f32, 1 inst
    return c.u;
}
__device__ __forceinline__ unsigned short cvt1(float a) {
    union { _Float16 h; unsigned short u; } c;
    c.h = (_Float16)a;                        // v_cvt_f16_f32 (RNE)
    return c.u;
}

// ---- prep: weights fp32 -> f16 packed in workspace (once per launch) ----
// ws layout: f16 w[80][64] (rows 0..7 q, 8..15 k, 16..79 v) = 10240 B, then f32 bias[80].
__global__ __launch_bounds__(256)
void prep_kernel(const float* __restrict__ wq, const float* __restrict__ bq,
                 const float* __restrict__ wk, const float* __restrict__ bk,
                 const float* __restrict__ wv, const float* __restrict__ bv,
                 unsigned short* __restrict__ ws)
{
    const int f = blockIdx.x * 256 + threadIdx.x;   // 0..767
    if (f < 640) {
        const int r = f >> 3, cw = (f & 7) * 8;
        const float* src = (r < 8)  ? (wq + r * 64 + cw)
                         : (r < 16) ? (wk + (r - 8) * 64 + cw)
                                    : (wv + (r - 16) * 64 + cw);
        const float4 w0 = *(const float4*)src;
        const float4 w1 = *(const float4*)(src + 4);
        uint4 pk;
        pk.x = pkh2(w0.x, w0.y); pk.y = pkh2(w0.z, w0.w);
        pk.z = pkh2(w1.x, w1.y); pk.w = pkh2(w1.z, w1.w);
        *(uint4*)(ws + r * 64 + cw) = pk;
    } else if (f < 720) {
        const int t = f - 640;
        const float bb = (t < 8) ? bq[t] : (t < 16) ? bk[t - 8] : bv[t - 16];
        ((float*)(ws + 5120))[t] = bb;
    }
}

// 512 threads, 50240 B LDS -> 3 blocks/CU = 24 waves/CU.
__global__ __launch_bounds__(512, 6)
void attn_win13_kernel(const float* __restrict__ x,
                       const unsigned short* __restrict__ ws,
                       float* __restrict__ out)
{
    // LDS: 16128 + 11520 + 320 + 16896 + 5376 = 50240 B -> 3 blocks/CU
    __shared__ __align__(16) unsigned short xT[VS * XS];    // f16 x, [vox][ch]
    __shared__ __align__(16) unsigned short wbf[80 * XS];   // f16 weights; attb aliases after P2
    __shared__ float ball[80];
    __shared__ __align__(16) unsigned short vpad[64 * VPS]; // f16 v, [ch][w*16+j], j=13..15 zeroed
    __shared__ __align__(16) unsigned short qkT[VS * QKTS]; // f16 q/k, [vox][ch] (0..7 q, 8..15 k)
    unsigned short* const attb = (unsigned short*)wbf;      // [w][16][16] f16 = 4096 B <= 11520

    const int tid = threadIdx.x;
    const int b   = blockIdx.y;
    const int v0  = blockIdx.x * VT;
    const size_t total = (size_t)512 * NTOT;

    // ---- P1: staging, split across waves. ----
    if (tid < 224) {
        // Waves 0..3: x -> f16 transposed LDS. Thread owns 8 ch x 4 vox:
        // 8 float4 loads (8x128B contiguous segments/instr), 16 pkrtz, 4 b128 writes
        // (quad-group (4vq+r+cg8)%8 uniform 8 lanes/group -> minimal conflicts).
        const int vq = tid >> 3, cg8 = tid & 7;
        const int c0 = cg8 * 8, vx = vq * 4;
        float xv[4][8];
#pragma unroll
        for (int i = 0; i < 8; ++i) {
            size_t idx = (size_t)(b * 64 + c0 + i) * NTOT + v0 + vx;
            if (idx > total - 4) idx = total - 4;   // clamp tail (garbage MFMA cols)
            const float4 t = *(const float4*)(x + idx);
            xv[0][i] = t.x; xv[1][i] = t.y; xv[2][i] = t.z; xv[3][i] = t.w;
        }
#pragma unroll
        for (int r = 0; r < 4; ++r) {
            uint4 pk;
            pk.x = pkh2(xv[r][0], xv[r][1]);
            pk.y = pkh2(xv[r][2], xv[r][3]);
            pk.z = pkh2(xv[r][4], xv[r][5]);
            pk.w = pkh2(xv[r][6], xv[r][7]);
            *(uint4*)(&xT[(vx + r) * XS + c0]) = pk;
        }
    } else if (tid >= 256) {
        // Waves 4..7: pre-packed f16 weights -> LDS (plain uint4 copies).
        int f = tid - 256;
#pragma unroll
        for (int it = 0; it < 3; ++it, f += 256) {
            if (f < 640) {
                const int r = f >> 3, cw = (f & 7) * 8;
                const uint4 pk = *(const uint4*)(ws + r * 64 + cw);
                *(uint4*)(&wbf[r * XS + cw]) = pk;
            }
        }
    }
    if (tid >= 432) {   // 80 bias loads
        const int t2 = tid - 432;
        ball[t2] = ((const float*)(ws + 5120))[t2];
    }
    {   // zero vpad pad cols j=13..15 (NaN hygiene for P4 A-frag): 64 rows x 8 windows
        const int r = tid >> 3, w = tid & 7;
        const int base = r * VPS + w * 16;
        vpad[base + 13] = 0;
        *(unsigned int*)(&vpad[base + 14]) = 0u;
    }
    __syncthreads();

    // ---- P2: projection GEMM, 5 mt x 7 nt = 35 tiles over 8 waves, K=64 (2 mfma).
    // A=xT (rows=vox), B=wbf (rows=ch): D row=(g*4+r)=vox-in-tile, col=ch.
    // mt==0 -> qkT[vox][ch] f16 scatter; mt>=1 -> vpad[ch][w*16+j] f16 scatter. ----
    {
        const int wid  = tid >> 6;
        const int lane = tid & 63;
        const int col  = lane & 15;
        const int g    = lane >> 4;
        for (int t = wid; t < 35; t += 8) {
            const int mt = t / 7, nt = t % 7;
            const f16x8 xa0 = *(const f16x8*)(&xT [(nt * 16 + col) * XS + g * 8]);
            const f16x8 wa0 = *(const f16x8*)(&wbf[(mt * 16 + col) * XS + g * 8]);
            const f16x8 xa1 = *(const f16x8*)(&xT [(nt * 16 + col) * XS + 32 + g * 8]);
            const f16x8 wa1 = *(const f16x8*)(&wbf[(mt * 16 + col) * XS + 32 + g * 8]);
            floatx4 acc = {0.f, 0.f, 0.f, 0.f};
            acc = __builtin_amdgcn_mfma_f32_16x16x32_f16(xa0, wa0, acc, 0, 0, 0);
            acc = __builtin_amdgcn_mfma_f32_16x16x32_f16(xa1, wa1, acc, 0, 0, 0);
            const int vox = nt * 16 + g * 4;
            if (mt == 0) {                    // q/k: ch=col (0..7 q, 8..15 k)
                const float qkb = ball[col];
#pragma unroll
                for (int r = 0; r < 4; ++r)
                    qkT[(vox + r) * QKTS + col] = cvt1(acc[r] + qkb);
            } else {                          // v: ch = (mt-1)*16+col
                const int c_out = (mt - 1) * 16 + col;
                const float vb = ball[16 + c_out];
                int w = vox / 13, j = vox - w * 13;
#pragma unroll
                for (int r = 0; r < 4; ++r) {
                    if (w < WPB) vpad[c_out * VPS + w * 16 + j] = cvt1(acc[r] + vb);
                    if (++j == 13) { j = 0; ++w; }
                }
            }
        }
    }
    __syncthreads();

    // ---- P3: scores via MFMA + fused in-register softmax. Wave w handles window w.
    // scores[i][j] = sum_{o<8} q[o][i]*k[o][j]: A = qkT[w13+col][0..15] (g<2),
    // B g=0 = qkT[w13+col][8..15] (k channels); other chunks zero. D: i=g*4+r, j=col.
    // Softmax over j = 16-lane shfl_xor reduce (j>=13 forced to -1e30 -> p=0). ----
    {
        const int w    = tid >> 6;           // window 0..7
        const int lane = tid & 63;
        const int col  = lane & 15;
        const int g    = lane >> 4;
        const f16x8 z = {};
        const f16x8 af = (g < 2) ? *(const f16x8*)(&qkT[(w * 13 + col) * QKTS + g * 8]) : z;
        const f16x8 bf = (g == 0) ? *(const f16x8*)(&qkT[(w * 13 + col) * QKTS + 8]) : z;
        floatx4 acc = {0.f, 0.f, 0.f, 0.f};
        acc = __builtin_amdgcn_mfma_f32_16x16x32_f16(af, bf, acc, 0, 0, 0);
#pragma unroll
        for (int r = 0; r < 4; ++r) {
            const float s = (col < 13) ? acc[r] : -1e30f;
            float m = s;
            m = fmaxf(m, __shfl_xor(m, 1));
            m = fmaxf(m, __shfl_xor(m, 2));
            m = fmaxf(m, __shfl_xor(m, 4));
            m = fmaxf(m, __shfl_xor(m, 8));
            const float e = __expf(s - m);
            float sum = e;
            sum += __shfl_xor(sum, 1);
            sum += __shfl_xor(sum, 2);
            sum += __shfl_xor(sum, 4);
            sum += __shfl_xor(sum, 8);
            attb[w * 256 + (g * 4 + r) * 16 + col] = cvt1(e / sum);
        }
    }
    __syncthreads();

    // ---- P4: out via MFMA. Wave w = window; 4 ct-quadrants of 16 channels.
    // D[c][i] = sum_j v[c][j]*att[i][j]: A=vpad rows (c=col), B=attb rows (i=col),
    // k=j padded 13->16; chunks g>=2: zero-B / dup-A. D: c=ct*16+g*4+r, i=col. ----
    {
        const int w    = tid >> 6;
        const int lane = tid & 63;
        const int col  = lane & 15;
        const int g    = lane >> 4;
        const int gA   = g & 1;
        const f16x8 z = {};
        const f16x8 bfrag = (g < 2) ? *(const f16x8*)(&attb[w * 256 + col * 16 + g * 8]) : z;
        const size_t obase = (size_t)(b * 64) * NTOT + v0 + w * 13 + col;
#pragma unroll
        for (int ct = 0; ct < 4; ++ct) {
            const f16x8 afrag = *(const f16x8*)(&vpad[(ct * 16 + col) * VPS + w * 16 + gA * 8]);
            floatx4 acc = {0.f, 0.f, 0.f, 0.f};
            acc = __builtin_amdgcn_mfma_f32_16x16x32_f16(afrag, bfrag, acc, 0, 0, 0);
            if (col < 13) {
                float* op = out + obase + (size_t)(ct * 16 + g * 4) * NTOT;
                op[0]                = acc[0];
                op[(size_t)NTOT]     = acc[1];
                op[(size_t)2 * NTOT] = acc[2];
                op[(size_t)3 * NTOT] = acc[3];
            }
        }
    }
}

extern "C" void kernel_launch(void* const* d_in, const int* in_sizes, int n_in,
                              void* d_out, int out_size, void* d_ws, size_t ws_size,
                              hipStream_t stream) {
    const float* x  = (const float*)d_in[0];
    const float* wq = (const float*)d_in[1];
    const float* bq = (const float*)d_in[2];
    const float* wk = (const float*)d_in[3];
    const float* bk = (const float*)d_in[4];
    const float* wv = (const float*)d_in[5];
    const float* bv = (const float*)d_in[6];
    float* out = (float*)d_out;
    unsigned short* ws = (unsigned short*)d_ws;   // 10560 B used

    prep_kernel<<<dim3(3), dim3(256), 0, stream>>>(wq, bq, wk, bk, wv, bv, ws);

    dim3 grid(NTOT / VT, 8);   // 512 tiles x 8 batches = 4096 blocks
    dim3 block(512);
    attn_win13_kernel<<<grid, block, 0, stream>>>(x, ws, out);
}